// Round 8
// baseline (135.255 us; speedup 1.0000x reference)
//
#include <hip/hip_runtime.h>
#include <math.h>

// Problem constants (fixed by the reference setup_inputs)
#define NIMG   64
#define CDIM   64
#define HWPX   4096
#define PARTS  8                 // 8 parts -> 17 MB partials fits ws (16 doesn't!)
#define KCL    128
#define PIXPART (HWPX / PARTS)   // 512 pixels per block
#define TL     32                // pixels per chunk
#define NCHUNK (PIXPART / TL)    // 16
#define SHIFT  10.0f             // softmax shift folded into bias
#define RSQRT128 0.08838834764831845f

// LDS strides in shorts (multiples of 8 so b128 stays 16B-aligned)
#define XP_S 72    // xp planes [32 p][64 c]
#define XC_S 40    // xc planes [64 c][32 p]
#define PH_S 40    // ph planes [128 k][32 p]

typedef __attribute__((ext_vector_type(8))) short short8; // 8 bf16
typedef __attribute__((ext_vector_type(4))) float f32x4;  // MFMA C/D

#define MFMA(a, b, c) __builtin_amdgcn_mfma_f32_16x16x32_bf16((a), (b), (c), 0, 0, 0)

// truncation split: hi = top16 bits, lo = bf16(f - hi). Dropped lo*lo term
// ~2^-16 relative -- well inside the 4.3e-4 output threshold.
__device__ __forceinline__ void tsplit(float f, short& hs, short& ls) {
    unsigned u = __builtin_bit_cast(unsigned, f);
    hs = (short)(u >> 16);
    float hf = __builtin_bit_cast(float, u & 0xffff0000u);
    ls = (short)(__builtin_bit_cast(unsigned, f - hf) >> 16);
}

// ---------------------------------------------------------------------------
// Kernel 1: ONE barrier per chunk. Double-buffered xp/xc/redA/sumP
// (parity = ch&1). The single barrier publishes both "sumP(ch) complete"
// and "stage(ch+1) complete". mm2's xc B-fragments are register-loaded
// BEFORE the barrier (they don't depend on the softmax denominator), so
// xc needs only 2 buffers. ph is wave-private (intra-wave transpose).
// NO device-scope fences here (round-6 lesson: __threadfence cost 3x).
// grid = NIMG*PARTS = 512 blocks of 256 threads, ~62 KB LDS, 2 blocks/CU.
// ---------------------------------------------------------------------------
__global__ __launch_bounds__(256, 2)
void netvlad_main(const float* __restrict__ x,       // [N][C][HW]
                  const float* __restrict__ conv_w,  // [K][C]
                  const float* __restrict__ conv_b,  // [K]
                  float* __restrict__ vout,          // partials or atomic acc
                  float* __restrict__ asout,
                  int use_atomic)
{
    __shared__ __align__(16) short xp_hi[2][TL * XP_S],  xp_lo[2][TL * XP_S];
    __shared__ __align__(16) short xc_hi[2][CDIM * XC_S], xc_lo[2][CDIM * XC_S];
    __shared__ __align__(16) short ph_hi[KCL * PH_S],  ph_lo[KCL * PH_S];
    __shared__ float redA[2][4 * 33];   // ssq partials [buf][wave][p] stride 33
    __shared__ float sumP[2][4 * TL];   // exp-sum partials [buf][wave][p]

    const int t   = threadIdx.x;
    const int w   = t >> 6;             // wave 0..3
    const int l   = t & 63;
    const int l15 = l & 15, l4 = l >> 4;
    const int n    = blockIdx.x >> 3;
    const int part = blockIdx.x & 7;
    const int p_s  = t & 31;            // staging pixel
    const int sg   = t >> 5;            // staging c-group (8 c's)

    // ---- W fragments in registers (once): A[m=k][kdim=c] ------------------
    short8 wh[2][2], wl[2][2];
    #pragma unroll
    for (int kt = 0; kt < 2; ++kt) {
        const int krow = (2 * w + kt) * 16 + l15;
        #pragma unroll
        for (int ks = 0; ks < 2; ++ks) {
            const float4* wp = (const float4*)(conv_w + krow * CDIM + ks * 32 + l4 * 8);
            float4 wa = wp[0], wb = wp[1];
            float wv[8] = {wa.x, wa.y, wa.z, wa.w, wb.x, wb.y, wb.z, wb.w};
            #pragma unroll
            for (int j = 0; j < 8; ++j) {
                short hs, ls; tsplit(wv[j], hs, ls);
                wh[kt][ks][j] = hs; wl[kt][ks][j] = ls;
            }
        }
    }
    // bias per D-row (k = (2w+kt)*16 + l4*4 + i), pre-shifted
    float cbr[2][4];
    #pragma unroll
    for (int kt = 0; kt < 2; ++kt)
        #pragma unroll
        for (int i = 0; i < 4; ++i)
            cbr[kt][i] = conv_b[(2 * w + kt) * 16 + l4 * 4 + i] - SHIFT;

    f32x4 acc2[2][4];                   // V tiles [kt][ct]
    #pragma unroll
    for (int a = 0; a < 2; ++a)
        #pragma unroll
        for (int b = 0; b < 4; ++b) acc2[a][b] = (f32x4)0.0f;
    float asr[2][4];                    // asum partials per D-row
    #pragma unroll
    for (int a = 0; a < 2; ++a)
        #pragma unroll
        for (int i = 0; i < 4; ++i) asr[a][i] = 0.f;

    const float* xbase = x + (size_t)n * CDIM * HWPX + part * PIXPART;

    // ---- prologue: stage chunk 0 into buffer 0 ----------------------------
    {
        float xv0[8], ssq = 0.f;
        #pragma unroll
        for (int j = 0; j < 8; ++j) {
            xv0[j] = xbase[(sg * 8 + j) * HWPX + p_s];
            ssq += xv0[j] * xv0[j];
        }
        ssq += __shfl_xor(ssq, 32);
        if (l < 32) redA[0][w * 33 + p_s] = ssq;
        short8 vh, vl;
        #pragma unroll
        for (int j = 0; j < 8; ++j) {
            short hs, ls; tsplit(xv0[j], hs, ls);
            vh[j] = hs; vl[j] = ls;
            xc_hi[0][(sg * 8 + j) * XC_S + p_s] = hs;
            xc_lo[0][(sg * 8 + j) * XC_S + p_s] = ls;
        }
        *(short8*)&xp_hi[0][p_s * XP_S + sg * 8] = vh;
        *(short8*)&xp_lo[0][p_s * XP_S + sg * 8] = vl;
    }
    __syncthreads();                                      // stage(0) published

    for (int ch = 0; ch < NCHUNK; ++ch) {
        const int b  = ch & 1;
        const int bn = b ^ 1;

        // 1. issue global prefetch for chunk ch+1
        float xv[8];
        if (ch + 1 < NCHUNK) {
            #pragma unroll
            for (int j = 0; j < 8; ++j)
                xv[j] = xbase[(sg * 8 + j) * HWPX + (ch + 1) * TL + p_s];
        }

        // 2. mm1: a1[kt][pt] = W @ Xraw  (reads xp[b]) ----------------------
        f32x4 a1[2][2];
        #pragma unroll
        for (int a = 0; a < 2; ++a)
            #pragma unroll
            for (int b2 = 0; b2 < 2; ++b2) a1[a][b2] = (f32x4)0.0f;
        #pragma unroll
        for (int ks = 0; ks < 2; ++ks) {
            #pragma unroll
            for (int pt = 0; pt < 2; ++pt) {
                short8 bh = *(short8*)&xp_hi[b][(pt * 16 + l15) * XP_S + ks * 32 + l4 * 8];
                short8 bl = *(short8*)&xp_lo[b][(pt * 16 + l15) * XP_S + ks * 32 + l4 * 8];
                #pragma unroll
                for (int kt = 0; kt < 2; ++kt) {
                    a1[kt][pt] = MFMA(wh[kt][ks], bh, a1[kt][pt]);
                    a1[kt][pt] = MFMA(wh[kt][ks], bl, a1[kt][pt]);
                    a1[kt][pt] = MFMA(wl[kt][ks], bh, a1[kt][pt]);
                }
            }
        }

        // 3. per-column 1/||x|| (reads redA[b]) -----------------------------
        float rn[2];
        #pragma unroll
        for (int pt = 0; pt < 2; ++pt) {
            const int col = pt * 16 + l15;
            float s0 = redA[b][col] + redA[b][33 + col];
            float s1 = redA[b][2 * 33 + col] + redA[b][3 * 33 + col];
            rn[pt] = 1.0f / fmaxf(sqrtf(s0 + s1), 1e-12f);
        }

        // 4. exp + wave-partial denominators (writes sumP[b]) ---------------
        float e[2][2][4], sp[2] = {0.f, 0.f};
        #pragma unroll
        for (int kt = 0; kt < 2; ++kt)
            #pragma unroll
            for (int pt = 0; pt < 2; ++pt)
                #pragma unroll
                for (int i = 0; i < 4; ++i) {
                    float ev = __expf(fmaf(a1[kt][pt][i], rn[pt], cbr[kt][i]));
                    e[kt][pt][i] = ev;
                    sp[pt] += ev;
                }
        #pragma unroll
        for (int pt = 0; pt < 2; ++pt) {
            sp[pt] += __shfl_xor(sp[pt], 16);
            sp[pt] += __shfl_xor(sp[pt], 32);     // wave-sum over its 32 k's
        }
        if (l4 == 0) {
            sumP[b][w * TL + l15]      = sp[0];
            sumP[b][w * TL + 16 + l15] = sp[1];
        }

        // 5. stage chunk ch+1 (writes xp/xc/redA[bn]) -----------------------
        if (ch + 1 < NCHUNK) {
            float ssq = 0.f;
            #pragma unroll
            for (int j = 0; j < 8; ++j) ssq += xv[j] * xv[j];
            ssq += __shfl_xor(ssq, 32);
            if (l < 32) redA[bn][w * 33 + p_s] = ssq;
            short8 vh, vl;
            #pragma unroll
            for (int j = 0; j < 8; ++j) {
                short hs, ls; tsplit(xv[j], hs, ls);
                vh[j] = hs; vl[j] = ls;
                xc_hi[bn][(sg * 8 + j) * XC_S + p_s] = hs;
                xc_lo[bn][(sg * 8 + j) * XC_S + p_s] = ls;
            }
            *(short8*)&xp_hi[bn][p_s * XP_S + sg * 8] = vh;
            *(short8*)&xp_lo[bn][p_s * XP_S + sg * 8] = vl;
        }

        // 6. preload mm2 B-fragments from xc[b] BEFORE the barrier ----------
        short8 xh2[4], xl2[4];
        #pragma unroll
        for (int ct = 0; ct < 4; ++ct) {
            xh2[ct] = *(short8*)&xc_hi[b][(ct * 16 + l15) * XC_S + l4 * 8];
            xl2[ct] = *(short8*)&xc_lo[b][(ct * 16 + l15) * XC_S + l4 * 8];
        }

        __syncthreads();   // publishes sumP(ch) AND stage(ch+1), all at once

        // 8. denominators (reads sumP[b]); P' -> ph (wave-private rows) -----
        float rden[2], rdn2[2];
        #pragma unroll
        for (int pt = 0; pt < 2; ++pt) {
            const int col = pt * 16 + l15;
            float den = sumP[b][col] + sumP[b][TL + col]
                      + sumP[b][2 * TL + col] + sumP[b][3 * TL + col];
            rden[pt] = 1.0f / den;
            rdn2[pt] = rden[pt] * rn[pt];          // fold 1/||x|| into P'
        }
        #pragma unroll
        for (int kt = 0; kt < 2; ++kt)
            #pragma unroll
            for (int i = 0; i < 4; ++i) {
                const int row = (2 * w + kt) * 16 + l4 * 4 + i;
                #pragma unroll
                for (int pt = 0; pt < 2; ++pt) {
                    float ev = e[kt][pt][i];
                    asr[kt][i] = fmaf(ev, rden[pt], asr[kt][i]);
                    float Pn = ev * rdn2[pt];
                    short hs, ls; tsplit(Pn, hs, ls);
                    ph_hi[row * PH_S + pt * 16 + l15] = hs;
                    ph_lo[row * PH_S + pt * 16 + l15] = ls;
                }
            }
        // no barrier: mm2 reads only the ph rows this wave just wrote
        // (intra-wave LDS ordering is guaranteed by the hardware/compiler).

        // 9. mm2: V[k][c] += P' @ Xraw^T ------------------------------------
        #pragma unroll
        for (int kt = 0; kt < 2; ++kt) {
            short8 ah = *(short8*)&ph_hi[((2 * w + kt) * 16 + l15) * PH_S + l4 * 8];
            short8 al = *(short8*)&ph_lo[((2 * w + kt) * 16 + l15) * PH_S + l4 * 8];
            #pragma unroll
            for (int ct = 0; ct < 4; ++ct) {
                acc2[kt][ct] = MFMA(ah, xh2[ct], acc2[kt][ct]);
                acc2[kt][ct] = MFMA(ah, xl2[ct], acc2[kt][ct]);
                acc2[kt][ct] = MFMA(al, xh2[ct], acc2[kt][ct]);
            }
        }
    }

    // ---- V write (coalesced: lanes l15 -> consecutive c) ------------------
    float* vg = use_atomic ? vout + (size_t)n * KCL * CDIM
                           : vout + (size_t)(n * PARTS + part) * KCL * CDIM;
    #pragma unroll
    for (int kt = 0; kt < 2; ++kt)
        #pragma unroll
        for (int ct = 0; ct < 4; ++ct)
            #pragma unroll
            for (int i = 0; i < 4; ++i) {
                const int row = (2 * w + kt) * 16 + l4 * 4 + i;
                const int col = ct * 16 + l15;
                if (use_atomic) atomicAdd(&vg[row * CDIM + col], acc2[kt][ct][i]);
                else            vg[row * CDIM + col] = acc2[kt][ct][i];
            }

    // ---- asum: reduce over l15 lanes, lane0-of-16 writes ------------------
    #pragma unroll
    for (int kt = 0; kt < 2; ++kt)
        #pragma unroll
        for (int i = 0; i < 4; ++i) {
            float v = asr[kt][i];
            v += __shfl_xor(v, 1); v += __shfl_xor(v, 2);
            v += __shfl_xor(v, 4); v += __shfl_xor(v, 8);
            if (l15 == 0) {
                const int row = (2 * w + kt) * 16 + l4 * 4 + i;
                if (use_atomic) atomicAdd(&asout[n * KCL + row], v);
                else            asout[(n * PARTS + part) * KCL + row] = v;
            }
        }
}

// ---------------------------------------------------------------------------
// Kernel 2: sum partials; vlad = V - asum*cent; intra-norm; global norm.
// After intra-norm every row has unit L2 norm -> global denom = sqrt(128).
// grid = NIMG*8 blocks x 256 threads; thread -> (k, 4 c's). Fully parallel.
// ---------------------------------------------------------------------------
__global__ __launch_bounds__(256)
void netvlad_finalize(const float* __restrict__ vpart,   // [N][nparts][K][C]
                      const float* __restrict__ aspart,  // [N][nparts][K]
                      const float* __restrict__ cent,    // [K][C]
                      float* __restrict__ out,           // [N][K*C]
                      int nparts)
{
    const int t = threadIdx.x;
    const int n  = blockIdx.x >> 3;
    const int kg = blockIdx.x & 7;
    const int k  = kg * 16 + (t >> 4);
    const int c0 = (t & 15) * 4;

    float vsum[4] = {0.f, 0.f, 0.f, 0.f};
    float av = 0.f;
    for (int pt = 0; pt < nparts; ++pt) {
        const float* vg = vpart + (((size_t)n * nparts + pt) * KCL + k) * CDIM + c0;
        float4 a = *(const float4*)vg;
        vsum[0] += a.x; vsum[1] += a.y; vsum[2] += a.z; vsum[3] += a.w;
        av += aspart[(n * nparts + pt) * KCL + k];
    }

    float4 cq = *(const float4*)(cent + k * CDIM + c0);
    float cc[4] = {cq.x, cq.y, cq.z, cq.w};
    float ss = 0.f;
    #pragma unroll
    for (int j = 0; j < 4; ++j) {
        vsum[j] -= av * cc[j];
        ss += vsum[j] * vsum[j];
    }
    // row sumsq over the 16 lanes covering this k
    ss += __shfl_xor(ss, 1); ss += __shfl_xor(ss, 2);
    ss += __shfl_xor(ss, 4); ss += __shfl_xor(ss, 8);
    const float s = (1.0f / fmaxf(sqrtf(ss), 1e-12f)) * RSQRT128;

    float4 o;
    o.x = vsum[0] * s; o.y = vsum[1] * s; o.z = vsum[2] * s; o.w = vsum[3] * s;
    *(float4*)(out + (size_t)n * KCL * CDIM + k * CDIM + c0) = o;
}

// ---------------------------------------------------------------------------
extern "C" void kernel_launch(void* const* d_in, const int* in_sizes, int n_in,
                              void* d_out, int out_size, void* d_ws, size_t ws_size,
                              hipStream_t stream) {
    const float* x     = (const float*)d_in[0];   // [64,64,64,64]
    const float* cent  = (const float*)d_in[1];   // [128,64]
    const float* convw = (const float*)d_in[2];   // [128,64]
    const float* convb = (const float*)d_in[3];   // [128]
    float* out = (float*)d_out;

    const size_t needP = (size_t)NIMG * PARTS * (KCL * CDIM + KCL) * sizeof(float);
    int nparts, use_atomic;
    if (ws_size >= needP) { nparts = PARTS; use_atomic = 0; }
    else                  { nparts = 1;     use_atomic = 1; }

    float* vws  = (float*)d_ws;                               // [N][nparts][K][C]
    float* asws = vws + (size_t)NIMG * nparts * KCL * CDIM;   // [N][nparts][K]
    if (use_atomic) {
        const size_t zb = (size_t)NIMG * (KCL * CDIM + KCL) * sizeof(float);
        hipMemsetAsync(d_ws, 0, zb, stream);
    }

    netvlad_main<<<dim3(NIMG * PARTS), dim3(256), 0, stream>>>(x, convw, convb, vws, asws, use_atomic);
    netvlad_finalize<<<dim3(NIMG * 8), dim3(256), 0, stream>>>(vws, asws, cent, out, nparts);
}